// Round 9
// baseline (157.940 us; speedup 1.0000x reference)
//
#include <hip/hip_runtime.h>
#include <hip/hip_bf16.h>
#include <stdint.h>

#define BATCH 4
#define SEQ   1024
#define DMODEL 1024
#define NH    16
#define DV    64

typedef short bf8 __attribute__((ext_vector_type(8)));   // 8 bf16 raw bits = 4 VGPRs
typedef float f4  __attribute__((ext_vector_type(4)));

static __device__ __forceinline__ short f2bf(float f) {
    union { float f; uint32_t u; } a; a.f = f;
    uint32_t r = a.u + 0x7FFF + ((a.u >> 16) & 1);   // RNE
    return (short)(r >> 16);
}

static __device__ __forceinline__ f4 mfma16(bf8 a, bf8 b, f4 c) {
    return __builtin_amdgcn_mfma_f32_16x16x32_bf16(a, b, c, 0, 0, 0);
}

// async global->LDS, 16B per lane; LDS dest is wave-uniform base + lane*16
static __device__ __forceinline__ void gload16(const short* g, short* l) {
    __builtin_amdgcn_global_load_lds((const __attribute__((address_space(1))) void*)g,
                                     (__attribute__((address_space(3))) void*)l,
                                     16, 0, 0);
}

// ---------------- prep kernel: weight transposes + x conversion, one launch ---------
// grid (32,32,7), block (32,8). z<3: transpose w_z (fp32->bf16 Wt). z>=3: cvt slice.

__global__ void prep_kernel(const float* __restrict__ x,
                            const float* __restrict__ wq, const float* __restrict__ wkv,
                            const float* __restrict__ wo,
                            short* __restrict__ xb,
                            short* __restrict__ wqkvt, short* __restrict__ wot) {
    int z = blockIdx.z;
    int tx = threadIdx.x, ty = threadIdx.y;          // (32,8)
    if (z >= 3) {
        // cvt slice z-3: 1024 blocks x 256 threads x 1 float4
        int i = (((z - 3) * 1024 + blockIdx.y * 32 + blockIdx.x) << 8) + ty * 32 + tx;
        float4 v = ((const float4*)x)[i];
        short4 o;
        o.x = f2bf(v.x); o.y = f2bf(v.y); o.z = f2bf(v.z); o.w = f2bf(v.w);
        ((short4*)xb)[i] = o;
        return;
    }
    __shared__ float tile[32][33];
    const float* w = (z == 0) ? wq : (z == 1) ? wkv : wo;
    short* wt = (z == 0) ? wqkvt : (z == 1) ? (wqkvt + (1u << 20)) : wot;
    int bx = blockIdx.x, by = blockIdx.y;
    #pragma unroll
    for (int i = 0; i < 4; i++)
        tile[ty + i * 8][tx] = w[(size_t)(by * 32 + ty + i * 8) * 1024 + bx * 32 + tx];
    __syncthreads();
    #pragma unroll
    for (int i = 0; i < 4; i++)
        wt[(size_t)(bx * 32 + ty + i * 8) * 1024 + by * 32 + tx] = f2bf(tile[tx][ty + i * 8]);
}

// ---------------- projection GEMM: xb (4096xK) * wqkvt^T, N=2048 --------------------
// Verified 16x16 m97-style 128x128 tile, BK=64, 4 waves 2x2, wave = 64x64.
// Bijective XCD-chunked swizzle (T1): per-XCD 8by x 8bx region (~4MB working set).

__global__ __launch_bounds__(256) void gemm_proj_kernel(
    const short* __restrict__ A, const short* __restrict__ Bt,
    const float* __restrict__ kw,
    short* __restrict__ q_out, short* __restrict__ kv_out, short* __restrict__ kvT_out)
{
    __shared__ short SM[32768];      // [buf0: As 8192 | Bs 8192][buf1: As | Bs] = 64 KB
    const int K = DMODEL;

    int tid = threadIdx.x;
    int wave = tid >> 6, lane = tid & 63;
    int quad = lane >> 4, l16 = lane & 15;

    // XCD swizzle: flat -> (xcd, pos); region = 8by x 8bx
    int flat = blockIdx.x + (blockIdx.y << 4);     // grid (16,32), 512 blocks
    int xcd = flat & 7, pos = flat >> 3;           // pos 0..63
    int nby = ((xcd >> 1) << 3) + (pos >> 3);      // 0..31
    int nbx = ((xcd & 1) << 3) + (pos & 7);        // 0..15
    int m0 = nby * 128;
    int n0 = nbx * 128;

    int wm = (wave >> 1) * 64;       // wave row offset in tile
    int wn = (wave & 1) * 64;        // wave col offset in tile
    int sw = l16 & 7;                // frag-read segment xor (row & 7)

    f4 acc[4][4] = {};

    auto stage = [&](int buf, int k0) {
        short* As = SM + buf * 16384;
        short* Bs = As + 8192;
        #pragma unroll
        for (int c = 0; c < 4; c++) {
            int flt = c * 256 + tid;                   // 0..1023 -> A 128x64
            int row = flt >> 3;                        // 0..127
            int seg = (flt & 7) ^ (row & 7);
            gload16(A + (size_t)(m0 + row) * K + k0 + seg * 8, As + flt * 8);
        }
        #pragma unroll
        for (int c = 0; c < 4; c++) {
            int flt = c * 256 + tid;                   // 0..1023 -> B 128x64
            int row = flt >> 3;
            int seg = (flt & 7) ^ (row & 7);
            gload16(Bt + (size_t)(n0 + row) * K + k0 + seg * 8, Bs + flt * 8);
        }
    };

    stage(0, 0);
    for (int k0 = 0; k0 < K; k0 += 64) {
        int buf = (k0 >> 6) & 1;
        __syncthreads();                               // buf's loads drained
        if (k0 + 64 < K) stage(buf ^ 1, k0 + 64);      // prefetch flies under compute
        const short* As = SM + buf * 16384;
        const short* Bs = As + 8192;
        #pragma unroll
        for (int kk = 0; kk < 2; kk++) {
            bf8 ar[4], br[4];
            #pragma unroll
            for (int i = 0; i < 4; i++)
                ar[i] = *(const bf8*)(As + (wm + i * 16 + l16) * 64 + ((kk * 4 + quad) ^ sw) * 8);
            #pragma unroll
            for (int j = 0; j < 4; j++)
                br[j] = *(const bf8*)(Bs + (wn + j * 16 + l16) * 64 + ((kk * 4 + quad) ^ sw) * 8);
            #pragma unroll
            for (int i = 0; i < 4; i++) {
                #pragma unroll
                for (int j = 0; j < 4; j++)
                    acc[i][j] = mfma16(ar[i], br[j], acc[i][j]);
            }
        }
    }

    // ---- epilogue (block-uniform branch: n0 is 128-aligned) ----
    if (n0 < 1024) {
        #pragma unroll
        for (int j = 0; j < 4; j++) {
            int n = n0 + wn + j * 16 + l16;
            float kws = 0.03125f * (1.0f + kw[n]);
            #pragma unroll
            for (int i = 0; i < 4; i++) {
                int mb = m0 + wm + i * 16 + quad * 4;
                q_out[(size_t)(mb + 0) * 1024 + n] = f2bf(acc[i][j][0] * kws);
                q_out[(size_t)(mb + 1) * 1024 + n] = f2bf(acc[i][j][1] * kws);
                q_out[(size_t)(mb + 2) * 1024 + n] = f2bf(acc[i][j][2] * kws);
                q_out[(size_t)(mb + 3) * 1024 + n] = f2bf(acc[i][j][3] * kws);
            }
        }
        return;
    }

    // kv row-major
    #pragma unroll
    for (int j = 0; j < 4; j++) {
        int n2 = n0 - 1024 + wn + j * 16 + l16;
        #pragma unroll
        for (int i = 0; i < 4; i++) {
            int mb = m0 + wm + i * 16 + quad * 4;
            kv_out[(size_t)(mb + 0) * 1024 + n2] = f2bf(acc[i][j][0]);
            kv_out[(size_t)(mb + 1) * 1024 + n2] = f2bf(acc[i][j][1]);
            kv_out[(size_t)(mb + 2) * 1024 + n2] = f2bf(acc[i][j][2]);
            kv_out[(size_t)(mb + 3) * 1024 + n2] = f2bf(acc[i][j][3]);
        }
    }

    // kvT via LDS transpose: waves 0,2 own n_local 0..63 (T0), waves 1,3 own 64..127 (T1).
    {
        const int TST = 136;               // row stride (shorts): 272 B, 16B-aligned
        short* T = SM;                     // 2 * 64 * 136 shorts = 34.8 KB <= 64 KB
        __syncthreads();                   // final-buf LDS reads complete before overwrite
        short* Tw = T + (wave & 1) * (64 * TST);
        #pragma unroll
        for (int j = 0; j < 4; j++) {
            int nl = j * 16 + l16;                     // n within the wave's 64-col slab
            #pragma unroll
            for (int i = 0; i < 4; i++) {
                short4 tv;
                tv.x = f2bf(acc[i][j][0]); tv.y = f2bf(acc[i][j][1]);
                tv.z = f2bf(acc[i][j][2]); tv.w = f2bf(acc[i][j][3]);
                *(short4*)(Tw + nl * TST + wm + i * 16 + quad * 4) = tv;
            }
        }
        __syncthreads();
        // cooperative coalesced store: 128 n-rows x 128 m-shorts = 2048 x 16B units
        int n2base = n0 - 1024;
        int mloc = m0 & 1023;              // column base within the 1024-long kvT row
        int bq = m0 >> 10;                 // batch index (uniform across the tile)
        #pragma unroll
        for (int c = 0; c < 8; c++) {
            int flt = c * 256 + tid;       // 0..2047
            int row = flt >> 4;            // 0..127 (n within tile)
            int seg = flt & 15;            // 16B unit within 256B m-row
            bf8 vseg = *(const bf8*)(T + (row >> 6) * (64 * TST) + (row & 63) * TST + seg * 8);
            int n2 = n2base + row;
            int bh = (bq << 4) + (n2 >> 6);
            *(bf8*)(kvT_out + (size_t)(bh * 64 + (n2 & 63)) * 1024 + mloc + seg * 8) = vseg;
        }
    }
}

// ---------------- output GEMM: yb (4096xK) * wot^T, N=1024 --------------------------
// Verified 16x16 128x128 structure + XCD-chunked swizzle (8by x 4bx per XCD).

__global__ __launch_bounds__(256) void gemm_out_kernel(
    const short* __restrict__ A, const short* __restrict__ Bt,
    float* __restrict__ c_out)
{
    __shared__ short SM[32768];
    const int K = DMODEL;

    int tid = threadIdx.x;
    int wave = tid >> 6, lane = tid & 63;
    int quad = lane >> 4, l16 = lane & 15;

    // XCD swizzle: grid (8,32) = 256 blocks; region = 8by x 4bx
    int flat = blockIdx.x + (blockIdx.y << 3);
    int xcd = flat & 7, pos = flat >> 3;           // pos 0..31
    int nby = ((xcd >> 1) << 3) + (pos >> 2);      // 0..31
    int nbx = ((xcd & 1) << 2) + (pos & 3);        // 0..7
    int m0 = nby * 128;
    int n0 = nbx * 128;

    int wm = (wave >> 1) * 64;
    int wn = (wave & 1) * 64;
    int sw = l16 & 7;

    f4 acc[4][4] = {};

    auto stage = [&](int buf, int k0) {
        short* As = SM + buf * 16384;
        short* Bs = As + 8192;
        #pragma unroll
        for (int c = 0; c < 4; c++) {
            int flt = c * 256 + tid;
            int row = flt >> 3;
            int seg = (flt & 7) ^ (row & 7);
            gload16(A + (size_t)(m0 + row) * K + k0 + seg * 8, As + flt * 8);
        }
        #pragma unroll
        for (int c = 0; c < 4; c++) {
            int flt = c * 256 + tid;
            int row = flt >> 3;
            int seg = (flt & 7) ^ (row & 7);
            gload16(Bt + (size_t)(n0 + row) * K + k0 + seg * 8, Bs + flt * 8);
        }
    };

    stage(0, 0);
    for (int k0 = 0; k0 < K; k0 += 64) {
        int buf = (k0 >> 6) & 1;
        __syncthreads();
        if (k0 + 64 < K) stage(buf ^ 1, k0 + 64);
        const short* As = SM + buf * 16384;
        const short* Bs = As + 8192;
        #pragma unroll
        for (int kk = 0; kk < 2; kk++) {
            bf8 ar[4], br[4];
            #pragma unroll
            for (int i = 0; i < 4; i++)
                ar[i] = *(const bf8*)(As + (wm + i * 16 + l16) * 64 + ((kk * 4 + quad) ^ sw) * 8);
            #pragma unroll
            for (int j = 0; j < 4; j++)
                br[j] = *(const bf8*)(Bs + (wn + j * 16 + l16) * 64 + ((kk * 4 + quad) ^ sw) * 8);
            #pragma unroll
            for (int i = 0; i < 4; i++) {
                #pragma unroll
                for (int j = 0; j < 4; j++)
                    acc[i][j] = mfma16(ar[i], br[j], acc[i][j]);
            }
        }
    }

    #pragma unroll
    for (int j = 0; j < 4; j++) {
        int n = n0 + wn + j * 16 + l16;
        #pragma unroll
        for (int i = 0; i < 4; i++) {
            int mb = m0 + wm + i * 16 + quad * 4;
            c_out[(size_t)(mb + 0) * 1024 + n] = acc[i][j][0];
            c_out[(size_t)(mb + 1) * 1024 + n] = acc[i][j][1];
            c_out[(size_t)(mb + 2) * 1024 + n] = acc[i][j][2];
            c_out[(size_t)(mb + 3) * 1024 + n] = acc[i][j][3];
        }
    }
}

// ---------------- flash attention (causal), SINGLE-CHAIN blocks, heavy-first --------
// RESTRUCTURED for occupancy: grid (16,64) = 1024 blocks = 4 blocks/CU = 4 waves/SIMD
// (was 8 pair-blocks = 2 blocks/CU = 2 waves/SIMD; round-7 counters showed all pipes
// idle -> latency-bound dependent chain; TLP is the matching lever, not LDS/VALU cuts).
// Block handles q-tile qt = 15 - blockIdx.x (heaviest first, LPT packing); tiles
// jt = 0..qt with diagonal mask only at jt == qt. Per-chain math identical to the
// verified chain-A path (absmax 0.015625). LDS 36.6 KB -> 4 blocks/CU fit.

#define PLD 72   // P row stride (shorts)

__global__ __launch_bounds__(256) void attn_kernel(
    const short* __restrict__ qg, const short* __restrict__ kvg,
    const short* __restrict__ kvTg, short* __restrict__ yg)
{
    int bh = blockIdx.y;
    int b = bh >> 4, h = bh & 15;
    int qt = 15 - blockIdx.x;               // heavy blocks first
    int tid = threadIdx.x;
    int wave = tid >> 6, lane = tid & 63;
    int quad = lane >> 4, l16 = lane & 15;
    int qa0 = qt * 64;
    int ntiles = qt + 1;

    __shared__ short Ks[2][64 * 64];        // [key][ch], swizzled, 8 KB each
    __shared__ short Vs[2][64 * 64];        // [vcol][key], swizzled
    __shared__ short Ps[4][16 * PLD];       // one P buffer per wave (2.3 KB each)
    short* myP = &Ps[wave][0];

    const short* qpa = qg + (size_t)(b * 1024 + qa0 + wave * 16 + l16) * 1024 + h * 64;
    bf8 qa_0 = *(const bf8*)(qpa + quad * 8);
    bf8 qa_1 = *(const bf8*)(qpa + 32 + quad * 8);

    bf8 ones;
    #pragma unroll
    for (int j = 0; j < 8; j++) ones[j] = (short)0x3F80;   // bf16 1.0

    f4 oa[4] = {};
    f4 lsa = {};
    int rowbase = qa0 + wave * 16 + quad * 4;

    auto stage = [&](int jt) {
        short* dstK = &Ks[jt & 1][0];
        short* dstV = &Vs[jt & 1][0];
        int j0 = jt * 64;
        #pragma unroll
        for (int k = 0; k < 2; k++) {
            int flat = k * 256 + tid;
            int row = flat >> 3;
            int lseg = (flat & 7) ^ (row & 7);
            gload16(kvg + (size_t)(b * 1024 + j0 + row) * 1024 + h * 64 + lseg * 8,
                    dstK + flat * 8);
            gload16(kvTg + (size_t)(bh * 64 + row) * 1024 + j0 + lseg * 8,
                    dstV + flat * 8);
        }
    };

    auto qk = [&](const short* K, f4 (&s)[4]) {
        #pragma unroll
        for (int c = 0; c < 4; c++) {
            int row = c * 16 + l16;
            int swz = row & 7;
            bf8 kb0 = *(const bf8*)(K + row * 64 + (quad ^ swz) * 8);
            bf8 kb1 = *(const bf8*)(K + row * 64 + (((quad + 4) ^ swz)) * 8);
            f4 t = {};
            t = mfma16(qa_0, kb0, t);
            t = mfma16(qa_1, kb1, t);
            s[c] = t;
        }
    };

    // unmasked expstore: tile fully below the diagonal (no predicates), f2bf RNE
    auto expstoreU = [&](f4 (&s)[4], short* P) {
        #pragma unroll
        for (int r = 0; r < 4; r++) {
            int prow = quad * 4 + r;
            P[prow * PLD + l16]      = f2bf(__expf(s[0][r]));
            P[prow * PLD + 16 + l16] = f2bf(__expf(s[1][r]));
            P[prow * PLD + 32 + l16] = f2bf(__expf(s[2][r]));
            P[prow * PLD + 48 + l16] = f2bf(__expf(s[3][r]));
        }
    };

    // masked expstore: diagonal tile only (jt == qt)
    auto expstoreM = [&](f4 (&s)[4], int j0, short* P) {
        #pragma unroll
        for (int r = 0; r < 4; r++) {
            int qi = rowbase + r;
            float p0 = (j0 + l16      <= qi) ? __expf(s[0][r]) : 0.0f;
            float p1 = (j0 + 16 + l16 <= qi) ? __expf(s[1][r]) : 0.0f;
            float p2 = (j0 + 32 + l16 <= qi) ? __expf(s[2][r]) : 0.0f;
            float p3 = (j0 + 48 + l16 <= qi) ? __expf(s[3][r]) : 0.0f;
            int prow = quad * 4 + r;
            P[prow * PLD + l16]      = f2bf(p0);
            P[prow * PLD + 16 + l16] = f2bf(p1);
            P[prow * PLD + 32 + l16] = f2bf(p2);
            P[prow * PLD + 48 + l16] = f2bf(p3);
        }
    };

    auto pv = [&](const short* P, const short* V) {
        bf8 pf0 = *(const bf8*)(P + l16 * PLD + quad * 8);
        bf8 pf1 = *(const bf8*)(P + l16 * PLD + 32 + quad * 8);
        lsa = mfma16(pf0, ones, lsa);
        lsa = mfma16(pf1, ones, lsa);
        #pragma unroll
        for (int t = 0; t < 4; t++) {
            int vrow = t * 16 + l16;
            int swz = vrow & 7;
            bf8 vb0 = *(const bf8*)(V + vrow * 64 + (quad ^ swz) * 8);
            bf8 vb1 = *(const bf8*)(V + vrow * 64 + (((quad + 4) ^ swz)) * 8);
            oa[t] = mfma16(pf0, vb0, oa[t]);
            oa[t] = mfma16(pf1, vb1, oa[t]);
        }
    };

    stage(0);

    for (int jt = 0; jt < ntiles; jt++) {
        __syncthreads();                       // drains vmcnt -> buf[jt&1] ready
        if (jt + 1 < ntiles) stage(jt + 1);
        const short* K = &Ks[jt & 1][0];
        const short* V = &Vs[jt & 1][0];
        int j0 = jt * 64;

        f4 sa[4];
        qk(K, sa);
        if (jt == qt) expstoreM(sa, j0, myP);  // diagonal
        else          expstoreU(sa, myP);
        pv(myP, V);
    }

    {
        float r0 = 1.0f / lsa[0], r1 = 1.0f / lsa[1], r2 = 1.0f / lsa[2], r3 = 1.0f / lsa[3];
        #pragma unroll
        for (int t = 0; t < 4; t++) {
            size_t base = (size_t)(b * SEQ + rowbase) * (NH * DV) + h * DV + t * 16 + l16;
            yg[base]                 = f2bf(oa[t][0] * r0);
            yg[base + 1 * (NH * DV)] = f2bf(oa[t][1] * r1);
            yg[base + 2 * (NH * DV)] = f2bf(oa[t][2] * r2);
            yg[base + 3 * (NH * DV)] = f2bf(oa[t][3] * r3);
        }
    }
}

// ---------------- launch ----------------

extern "C" void kernel_launch(void* const* d_in, const int* in_sizes, int n_in,
                              void* d_out, int out_size, void* d_ws, size_t ws_size,
                              hipStream_t stream) {
    const float* x    = (const float*)d_in[0];
    const float* w_q  = (const float*)d_in[1];
    const float* w_kv = (const float*)d_in[2];
    const float* w_o  = (const float*)d_in[3];
    const float* kw   = (const float*)d_in[4];
    float* out = (float*)d_out;

    char* ws = (char*)d_ws;
    short* xb    = (short*)(ws);                        // 4096x1024 bf16 : 8 MB
    short* wqkvt = (short*)(ws + ( 8u << 20));          // 2048x1024 bf16 : 4 MB
    short* wot   = (short*)(ws + (12u << 20));          // 1024x1024 bf16 : 2 MB
    short* qp    = (short*)(ws + (14u << 20));          // q' [4096][1024] : 8 MB
    short* kvb   = (short*)(ws + (22u << 20));          // kv [4096][1024] : 8 MB
    short* kvT   = (short*)(ws + (30u << 20));          // kvT [64bh*64v][1024 l] : 8 MB
    short* yb    = (short*)(ws + (38u << 20));          // y  [4096][1024] : 8 MB

    // weights transpose + x conversion, single launch
    prep_kernel<<<dim3(32, 32, 7), dim3(32, 8), 0, stream>>>(
        x, w_q, w_kv, w_o, xb, wqkvt, wot);

    // projections: M=4096, N=2048, K=1024 -> q' (kw folded), kv, kvT (LDS-transposed)
    // 128x128 tiles, 64x64/wave, dbuf, XCD-chunked swizzle: grid (16,32)
    gemm_proj_kernel<<<dim3(16, 32), 256, 0, stream>>>(
        xb, wqkvt, kw, qp, kvb, kvT);

    // attention: single-chain blocks, heavy-first, 4 blocks/CU, dbuf staging
    attn_kernel<<<dim3(16, BATCH * NH), 256, 0, stream>>>(qp, kvb, kvT, yb);

    // output: M=4096, N=1024, K=1024 (128x128 tiles, dbuf, XCD-chunked swizzle)
    gemm_out_kernel<<<dim3(8, 32), 256, 0, stream>>>(yb, wot, out);
}

// Round 10
// 143.372 us; speedup vs baseline: 1.1016x; 1.1016x over previous
//
#include <hip/hip_runtime.h>
#include <hip/hip_bf16.h>
#include <stdint.h>

#define BATCH 4
#define SEQ   1024
#define DMODEL 1024
#define NH    16
#define DV    64

typedef short bf8 __attribute__((ext_vector_type(8)));   // 8 bf16 raw bits = 4 VGPRs
typedef float f4  __attribute__((ext_vector_type(4)));

static __device__ __forceinline__ short f2bf(float f) {
    union { float f; uint32_t u; } a; a.f = f;
    uint32_t r = a.u + 0x7FFF + ((a.u >> 16) & 1);   // RNE
    return (short)(r >> 16);
}

static __device__ __forceinline__ f4 mfma16(bf8 a, bf8 b, f4 c) {
    return __builtin_amdgcn_mfma_f32_16x16x32_bf16(a, b, c, 0, 0, 0);
}

// async global->LDS, 16B per lane; LDS dest is wave-uniform base + lane*16
static __device__ __forceinline__ void gload16(const short* g, short* l) {
    __builtin_amdgcn_global_load_lds((const __attribute__((address_space(1))) void*)g,
                                     (__attribute__((address_space(3))) void*)l,
                                     16, 0, 0);
}

// ---------------- prep kernel: weight transposes + x conversion, one launch ---------
// grid (32,32,7), block (32,8). z<3: transpose w_z (fp32->bf16 Wt). z>=3: cvt slice.

__global__ void prep_kernel(const float* __restrict__ x,
                            const float* __restrict__ wq, const float* __restrict__ wkv,
                            const float* __restrict__ wo,
                            short* __restrict__ xb,
                            short* __restrict__ wqkvt, short* __restrict__ wot) {
    int z = blockIdx.z;
    int tx = threadIdx.x, ty = threadIdx.y;          // (32,8)
    if (z >= 3) {
        // cvt slice z-3: 1024 blocks x 256 threads x 1 float4
        int i = (((z - 3) * 1024 + blockIdx.y * 32 + blockIdx.x) << 8) + ty * 32 + tx;
        float4 v = ((const float4*)x)[i];
        short4 o;
        o.x = f2bf(v.x); o.y = f2bf(v.y); o.z = f2bf(v.z); o.w = f2bf(v.w);
        ((short4*)xb)[i] = o;
        return;
    }
    __shared__ float tile[32][33];
    const float* w = (z == 0) ? wq : (z == 1) ? wkv : wo;
    short* wt = (z == 0) ? wqkvt : (z == 1) ? (wqkvt + (1u << 20)) : wot;
    int bx = blockIdx.x, by = blockIdx.y;
    #pragma unroll
    for (int i = 0; i < 4; i++)
        tile[ty + i * 8][tx] = w[(size_t)(by * 32 + ty + i * 8) * 1024 + bx * 32 + tx];
    __syncthreads();
    #pragma unroll
    for (int i = 0; i < 4; i++)
        wt[(size_t)(bx * 32 + ty + i * 8) * 1024 + by * 32 + tx] = f2bf(tile[tx][ty + i * 8]);
}

// ---------------- projection GEMM: xb (4096xK) * wqkvt^T, N=2048 --------------------
// Verified 16x16 m97-style 128x128 tile, BK=64, 4 waves 2x2, wave = 64x64.
// Bijective XCD-chunked swizzle (T1): per-XCD 8by x 8bx region (~4MB working set).

__global__ __launch_bounds__(256) void gemm_proj_kernel(
    const short* __restrict__ A, const short* __restrict__ Bt,
    const float* __restrict__ kw,
    short* __restrict__ q_out, short* __restrict__ kv_out, short* __restrict__ kvT_out)
{
    __shared__ short SM[32768];      // [buf0: As 8192 | Bs 8192][buf1: As | Bs] = 64 KB
    const int K = DMODEL;

    int tid = threadIdx.x;
    int wave = tid >> 6, lane = tid & 63;
    int quad = lane >> 4, l16 = lane & 15;

    // XCD swizzle: flat -> (xcd, pos); region = 8by x 8bx
    int flat = blockIdx.x + (blockIdx.y << 4);     // grid (16,32), 512 blocks
    int xcd = flat & 7, pos = flat >> 3;           // pos 0..63
    int nby = ((xcd >> 1) << 3) + (pos >> 3);      // 0..31
    int nbx = ((xcd & 1) << 3) + (pos & 7);        // 0..15
    int m0 = nby * 128;
    int n0 = nbx * 128;

    int wm = (wave >> 1) * 64;       // wave row offset in tile
    int wn = (wave & 1) * 64;        // wave col offset in tile
    int sw = l16 & 7;                // frag-read segment xor (row & 7)

    f4 acc[4][4] = {};

    auto stage = [&](int buf, int k0) {
        short* As = SM + buf * 16384;
        short* Bs = As + 8192;
        #pragma unroll
        for (int c = 0; c < 4; c++) {
            int flt = c * 256 + tid;                   // 0..1023 -> A 128x64
            int row = flt >> 3;                        // 0..127
            int seg = (flt & 7) ^ (row & 7);
            gload16(A + (size_t)(m0 + row) * K + k0 + seg * 8, As + flt * 8);
        }
        #pragma unroll
        for (int c = 0; c < 4; c++) {
            int flt = c * 256 + tid;                   // 0..1023 -> B 128x64
            int row = flt >> 3;
            int seg = (flt & 7) ^ (row & 7);
            gload16(Bt + (size_t)(n0 + row) * K + k0 + seg * 8, Bs + flt * 8);
        }
    };

    stage(0, 0);
    for (int k0 = 0; k0 < K; k0 += 64) {
        int buf = (k0 >> 6) & 1;
        __syncthreads();                               // buf's loads drained
        if (k0 + 64 < K) stage(buf ^ 1, k0 + 64);      // prefetch flies under compute
        const short* As = SM + buf * 16384;
        const short* Bs = As + 8192;
        #pragma unroll
        for (int kk = 0; kk < 2; kk++) {
            bf8 ar[4], br[4];
            #pragma unroll
            for (int i = 0; i < 4; i++)
                ar[i] = *(const bf8*)(As + (wm + i * 16 + l16) * 64 + ((kk * 4 + quad) ^ sw) * 8);
            #pragma unroll
            for (int j = 0; j < 4; j++)
                br[j] = *(const bf8*)(Bs + (wn + j * 16 + l16) * 64 + ((kk * 4 + quad) ^ sw) * 8);
            #pragma unroll
            for (int i = 0; i < 4; i++) {
                #pragma unroll
                for (int j = 0; j < 4; j++)
                    acc[i][j] = mfma16(ar[i], br[j], acc[i][j]);
            }
        }
    }

    // ---- epilogue (block-uniform branch: n0 is 128-aligned) ----
    if (n0 < 1024) {
        #pragma unroll
        for (int j = 0; j < 4; j++) {
            int n = n0 + wn + j * 16 + l16;
            float kws = 0.03125f * (1.0f + kw[n]);
            #pragma unroll
            for (int i = 0; i < 4; i++) {
                int mb = m0 + wm + i * 16 + quad * 4;
                q_out[(size_t)(mb + 0) * 1024 + n] = f2bf(acc[i][j][0] * kws);
                q_out[(size_t)(mb + 1) * 1024 + n] = f2bf(acc[i][j][1] * kws);
                q_out[(size_t)(mb + 2) * 1024 + n] = f2bf(acc[i][j][2] * kws);
                q_out[(size_t)(mb + 3) * 1024 + n] = f2bf(acc[i][j][3] * kws);
            }
        }
        return;
    }

    // kv row-major
    #pragma unroll
    for (int j = 0; j < 4; j++) {
        int n2 = n0 - 1024 + wn + j * 16 + l16;
        #pragma unroll
        for (int i = 0; i < 4; i++) {
            int mb = m0 + wm + i * 16 + quad * 4;
            kv_out[(size_t)(mb + 0) * 1024 + n2] = f2bf(acc[i][j][0]);
            kv_out[(size_t)(mb + 1) * 1024 + n2] = f2bf(acc[i][j][1]);
            kv_out[(size_t)(mb + 2) * 1024 + n2] = f2bf(acc[i][j][2]);
            kv_out[(size_t)(mb + 3) * 1024 + n2] = f2bf(acc[i][j][3]);
        }
    }

    // kvT via LDS transpose: waves 0,2 own n_local 0..63 (T0), waves 1,3 own 64..127 (T1).
    {
        const int TST = 136;               // row stride (shorts): 272 B, 16B-aligned
        short* T = SM;                     // 2 * 64 * 136 shorts = 34.8 KB <= 64 KB
        __syncthreads();                   // final-buf LDS reads complete before overwrite
        short* Tw = T + (wave & 1) * (64 * TST);
        #pragma unroll
        for (int j = 0; j < 4; j++) {
            int nl = j * 16 + l16;                     // n within the wave's 64-col slab
            #pragma unroll
            for (int i = 0; i < 4; i++) {
                short4 tv;
                tv.x = f2bf(acc[i][j][0]); tv.y = f2bf(acc[i][j][1]);
                tv.z = f2bf(acc[i][j][2]); tv.w = f2bf(acc[i][j][3]);
                *(short4*)(Tw + nl * TST + wm + i * 16 + quad * 4) = tv;
            }
        }
        __syncthreads();
        // cooperative coalesced store: 128 n-rows x 128 m-shorts = 2048 x 16B units
        int n2base = n0 - 1024;
        int mloc = m0 & 1023;              // column base within the 1024-long kvT row
        int bq = m0 >> 10;                 // batch index (uniform across the tile)
        #pragma unroll
        for (int c = 0; c < 8; c++) {
            int flt = c * 256 + tid;       // 0..2047
            int row = flt >> 4;            // 0..127 (n within tile)
            int seg = flt & 15;            // 16B unit within 256B m-row
            bf8 vseg = *(const bf8*)(T + (row >> 6) * (64 * TST) + (row & 63) * TST + seg * 8);
            int n2 = n2base + row;
            int bh = (bq << 4) + (n2 >> 6);
            *(bf8*)(kvT_out + (size_t)(bh * 64 + (n2 & 63)) * 1024 + mloc + seg * 8) = vseg;
        }
    }
}

// ---------------- output GEMM: yb (4096xK) * wot^T, N=1024 --------------------------
// Verified 16x16 128x128 structure + XCD-chunked swizzle (8by x 4bx per XCD).

__global__ __launch_bounds__(256) void gemm_out_kernel(
    const short* __restrict__ A, const short* __restrict__ Bt,
    float* __restrict__ c_out)
{
    __shared__ short SM[32768];
    const int K = DMODEL;

    int tid = threadIdx.x;
    int wave = tid >> 6, lane = tid & 63;
    int quad = lane >> 4, l16 = lane & 15;

    // XCD swizzle: grid (8,32) = 256 blocks; region = 8by x 4bx
    int flat = blockIdx.x + (blockIdx.y << 3);
    int xcd = flat & 7, pos = flat >> 3;           // pos 0..31
    int nby = ((xcd >> 1) << 3) + (pos >> 2);      // 0..31
    int nbx = ((xcd & 1) << 2) + (pos & 3);        // 0..7
    int m0 = nby * 128;
    int n0 = nbx * 128;

    int wm = (wave >> 1) * 64;
    int wn = (wave & 1) * 64;
    int sw = l16 & 7;

    f4 acc[4][4] = {};

    auto stage = [&](int buf, int k0) {
        short* As = SM + buf * 16384;
        short* Bs = As + 8192;
        #pragma unroll
        for (int c = 0; c < 4; c++) {
            int flt = c * 256 + tid;
            int row = flt >> 3;
            int seg = (flt & 7) ^ (row & 7);
            gload16(A + (size_t)(m0 + row) * K + k0 + seg * 8, As + flt * 8);
        }
        #pragma unroll
        for (int c = 0; c < 4; c++) {
            int flt = c * 256 + tid;
            int row = flt >> 3;
            int seg = (flt & 7) ^ (row & 7);
            gload16(Bt + (size_t)(n0 + row) * K + k0 + seg * 8, Bs + flt * 8);
        }
    };

    stage(0, 0);
    for (int k0 = 0; k0 < K; k0 += 64) {
        int buf = (k0 >> 6) & 1;
        __syncthreads();
        if (k0 + 64 < K) stage(buf ^ 1, k0 + 64);
        const short* As = SM + buf * 16384;
        const short* Bs = As + 8192;
        #pragma unroll
        for (int kk = 0; kk < 2; kk++) {
            bf8 ar[4], br[4];
            #pragma unroll
            for (int i = 0; i < 4; i++)
                ar[i] = *(const bf8*)(As + (wm + i * 16 + l16) * 64 + ((kk * 4 + quad) ^ sw) * 8);
            #pragma unroll
            for (int j = 0; j < 4; j++)
                br[j] = *(const bf8*)(Bs + (wn + j * 16 + l16) * 64 + ((kk * 4 + quad) ^ sw) * 8);
            #pragma unroll
            for (int i = 0; i < 4; i++) {
                #pragma unroll
                for (int j = 0; j < 4; j++)
                    acc[i][j] = mfma16(ar[i], br[j], acc[i][j]);
            }
        }
    }

    #pragma unroll
    for (int j = 0; j < 4; j++) {
        int n = n0 + wn + j * 16 + l16;
        #pragma unroll
        for (int i = 0; i < 4; i++) {
            int mb = m0 + wm + i * 16 + quad * 4;
            c_out[(size_t)(mb + 0) * 1024 + n] = acc[i][j][0];
            c_out[(size_t)(mb + 1) * 1024 + n] = acc[i][j][1];
            c_out[(size_t)(mb + 2) * 1024 + n] = acc[i][j][2];
            c_out[(size_t)(mb + 3) * 1024 + n] = acc[i][j][3];
        }
    }
}

// ---------------- flash attention (causal), pair-balanced, CHAIN-MERGED -------------
// REVERTED to the pair structure (single-chain split measured +10us: staging traffic
// Sum(qt+1)=136 vs pair Sum(16-x)=100 tile-stages/bh, FETCH 55MB). NEW: bh-colocating
// XCD swizzle -- the 8 pair-blocks of one bh share w mod 8 -> same XCD -> the bh's
// 256KB kv+kvT is fetched ~once per XCD and L2-reused; tile prefetch latency becomes
// L2-hit class (~200cy) instead of HBM (~900cy), matching the measured all-pipes-idle
// latency bound.

#define PLD 72   // P row stride (shorts)

__global__ __launch_bounds__(256) void attn_kernel(
    const short* __restrict__ qg, const short* __restrict__ kvg,
    const short* __restrict__ kvTg, short* __restrict__ yg)
{
    // bh-colocating swizzle: w = x + 8y (0..511); all blocks of a bh have equal w&7
    int w = blockIdx.x + (blockIdx.y << 3);
    int bh = ((w >> 6) << 3) + (w & 7);     // 0..63
    int x = (w >> 3) & 7;                   // pair index 0..7
    int b = bh >> 4, h = bh & 15;
    int tid = threadIdx.x;
    int wave = tid >> 6, lane = tid & 63;
    int quad = lane >> 4, l16 = lane & 15;
    int qa0 = x * 64;
    int qb0 = (15 - x) * 64;
    int ntiles = 16 - x;

    __shared__ short Ks[2][64 * 64];        // [key][ch], swizzled, 8 KB each
    __shared__ short Vs[2][64 * 64];        // [vcol][key], swizzled
    __shared__ short Ps[4][2 * 16 * PLD];   // two P buffers per wave
    short* myPB = &Ps[wave][0];
    short* myPA = &Ps[wave][16 * PLD];

    const short* qpa = qg + (size_t)(b * 1024 + qa0 + wave * 16 + l16) * 1024 + h * 64;
    const short* qpb = qg + (size_t)(b * 1024 + qb0 + wave * 16 + l16) * 1024 + h * 64;
    bf8 qa_0 = *(const bf8*)(qpa + quad * 8);
    bf8 qa_1 = *(const bf8*)(qpa + 32 + quad * 8);
    bf8 qb_0 = *(const bf8*)(qpb + quad * 8);
    bf8 qb_1 = *(const bf8*)(qpb + 32 + quad * 8);

    bf8 ones;
    #pragma unroll
    for (int j = 0; j < 8; j++) ones[j] = (short)0x3F80;   // bf16 1.0

    f4 oa[4] = {}, ob[4] = {};
    f4 lsa = {}, lsb = {};
    int rowbaseA = qa0 + wave * 16 + quad * 4;
    int rowbaseB = qb0 + wave * 16 + quad * 4;

    auto stage = [&](int jt) {
        short* dstK = &Ks[jt & 1][0];
        short* dstV = &Vs[jt & 1][0];
        int j0 = jt * 64;
        #pragma unroll
        for (int k = 0; k < 2; k++) {
            int flat = k * 256 + tid;
            int row = flat >> 3;
            int lseg = (flat & 7) ^ (row & 7);
            gload16(kvg + (size_t)(b * 1024 + j0 + row) * 1024 + h * 64 + lseg * 8,
                    dstK + flat * 8);
            gload16(kvTg + (size_t)(bh * 64 + row) * 1024 + j0 + lseg * 8,
                    dstV + flat * 8);
        }
    };

    auto qk = [&](bf8 qf0, bf8 qf1, const short* K, f4 (&s)[4]) {
        #pragma unroll
        for (int c = 0; c < 4; c++) {
            int row = c * 16 + l16;
            int swz = row & 7;
            bf8 kb0 = *(const bf8*)(K + row * 64 + (quad ^ swz) * 8);
            bf8 kb1 = *(const bf8*)(K + row * 64 + (((quad + 4) ^ swz)) * 8);
            f4 t = {};
            t = mfma16(qf0, kb0, t);
            t = mfma16(qf1, kb1, t);
            s[c] = t;
        }
    };

    // unmasked expstore: tile fully below the diagonal (no predicates), f2bf RNE
    auto expstoreU = [&](f4 (&s)[4], short* P) {
        #pragma unroll
        for (int r = 0; r < 4; r++) {
            int prow = quad * 4 + r;
            P[prow * PLD + l16]      = f2bf(__expf(s[0][r]));
            P[prow * PLD + 16 + l16] = f2bf(__expf(s[1][r]));
            P[prow * PLD + 32 + l16] = f2bf(__expf(s[2][r]));
            P[prow * PLD + 48 + l16] = f2bf(__expf(s[3][r]));
        }
    };

    // masked expstore: diagonal tile only (2 of 17 chain-tiles per block)
    auto expstoreM = [&](f4 (&s)[4], int rowbase, int j0, short* P) {
        #pragma unroll
        for (int r = 0; r < 4; r++) {
            int qi = rowbase + r;
            float p0 = (j0 + l16      <= qi) ? __expf(s[0][r]) : 0.0f;
            float p1 = (j0 + 16 + l16 <= qi) ? __expf(s[1][r]) : 0.0f;
            float p2 = (j0 + 32 + l16 <= qi) ? __expf(s[2][r]) : 0.0f;
            float p3 = (j0 + 48 + l16 <= qi) ? __expf(s[3][r]) : 0.0f;
            int prow = quad * 4 + r;
            P[prow * PLD + l16]      = f2bf(p0);
            P[prow * PLD + 16 + l16] = f2bf(p1);
            P[prow * PLD + 32 + l16] = f2bf(p2);
            P[prow * PLD + 48 + l16] = f2bf(p3);
        }
    };

    auto pv = [&](const short* P, const short* V, f4 (&o)[4], f4& lsum) {
        bf8 pf0 = *(const bf8*)(P + l16 * PLD + quad * 8);
        bf8 pf1 = *(const bf8*)(P + l16 * PLD + 32 + quad * 8);
        lsum = mfma16(pf0, ones, lsum);
        lsum = mfma16(pf1, ones, lsum);
        #pragma unroll
        for (int t = 0; t < 4; t++) {
            int vrow = t * 16 + l16;
            int swz = vrow & 7;
            bf8 vb0 = *(const bf8*)(V + vrow * 64 + (quad ^ swz) * 8);
            bf8 vb1 = *(const bf8*)(V + vrow * 64 + (((quad + 4) ^ swz)) * 8);
            o[t] = mfma16(pf0, vb0, o[t]);
            o[t] = mfma16(pf1, vb1, o[t]);
        }
    };

    stage(0);

    for (int jt = 0; jt < ntiles; jt++) {
        __syncthreads();                       // drains vmcnt -> buf[jt&1] ready
        if (jt + 1 < ntiles) stage(jt + 1);
        const short* K = &Ks[jt & 1][0];
        const short* V = &Vs[jt & 1][0];
        int j0 = jt * 64;
        bool doA = (jt <= x);                  // block-uniform branch

        if (doA) {
            // ---- merged QK: one K-fragment read feeds both chains ----
            f4 sb[4], sa[4];
            #pragma unroll
            for (int c = 0; c < 4; c++) {
                int row = c * 16 + l16;
                int swz = row & 7;
                bf8 kb0 = *(const bf8*)(K + row * 64 + (quad ^ swz) * 8);
                bf8 kb1 = *(const bf8*)(K + row * 64 + (((quad + 4) ^ swz)) * 8);
                f4 tb = {};
                tb = mfma16(qb_0, kb0, tb);
                tb = mfma16(qb_1, kb1, tb);
                sb[c] = tb;
                f4 ta = {};
                ta = mfma16(qa_0, kb0, ta);
                ta = mfma16(qa_1, kb1, ta);
                sa[c] = ta;
            }
            // B is never diagonal here (diag_B = 15-x >= 8 > x >= jt)
            expstoreU(sb, myPB);
            if (jt == x) expstoreM(sa, rowbaseA, j0, myPA);   // A diagonal
            else         expstoreU(sa, myPA);
            // ---- merged PV: one V-fragment read feeds both chains ----
            bf8 pb0 = *(const bf8*)(myPB + l16 * PLD + quad * 8);
            bf8 pb1 = *(const bf8*)(myPB + l16 * PLD + 32 + quad * 8);
            bf8 pa0 = *(const bf8*)(myPA + l16 * PLD + quad * 8);
            bf8 pa1 = *(const bf8*)(myPA + l16 * PLD + 32 + quad * 8);
            lsb = mfma16(pb0, ones, lsb);
            lsb = mfma16(pb1, ones, lsb);
            lsa = mfma16(pa0, ones, lsa);
            lsa = mfma16(pa1, ones, lsa);
            #pragma unroll
            for (int t = 0; t < 4; t++) {
                int vrow = t * 16 + l16;
                int swz = vrow & 7;
                bf8 vb0 = *(const bf8*)(V + vrow * 64 + (quad ^ swz) * 8);
                bf8 vb1 = *(const bf8*)(V + vrow * 64 + (((quad + 4) ^ swz)) * 8);
                ob[t] = mfma16(pb0, vb0, ob[t]);
                ob[t] = mfma16(pb1, vb1, ob[t]);
                oa[t] = mfma16(pa0, vb0, oa[t]);
                oa[t] = mfma16(pa1, vb1, oa[t]);
            }
        } else {
            f4 sb[4];
            qk(qb_0, qb_1, K, sb);
            if (jt == ntiles - 1) expstoreM(sb, rowbaseB, j0, myPB);  // B diagonal
            else                  expstoreU(sb, myPB);
            pv(myPB, V, ob, lsb);
        }
    }

    {
        float r0 = 1.0f / lsa[0], r1 = 1.0f / lsa[1], r2 = 1.0f / lsa[2], r3 = 1.0f / lsa[3];
        #pragma unroll
        for (int t = 0; t < 4; t++) {
            size_t base = (size_t)(b * SEQ + rowbaseA) * (NH * DV) + h * DV + t * 16 + l16;
            yg[base]                 = f2bf(oa[t][0] * r0);
            yg[base + 1 * (NH * DV)] = f2bf(oa[t][1] * r1);
            yg[base + 2 * (NH * DV)] = f2bf(oa[t][2] * r2);
            yg[base + 3 * (NH * DV)] = f2bf(oa[t][3] * r3);
        }
    }
    {
        float r0 = 1.0f / lsb[0], r1 = 1.0f / lsb[1], r2 = 1.0f / lsb[2], r3 = 1.0f / lsb[3];
        #pragma unroll
        for (int t = 0; t < 4; t++) {
            size_t base = (size_t)(b * SEQ + rowbaseB) * (NH * DV) + h * DV + t * 16 + l16;
            yg[base]                 = f2bf(ob[t][0] * r0);
            yg[base + 1 * (NH * DV)] = f2bf(ob[t][1] * r1);
            yg[base + 2 * (NH * DV)] = f2bf(ob[t][2] * r2);
            yg[base + 3 * (NH * DV)] = f2bf(ob[t][3] * r3);
        }
    }
}

// ---------------- launch ----------------

extern "C" void kernel_launch(void* const* d_in, const int* in_sizes, int n_in,
                              void* d_out, int out_size, void* d_ws, size_t ws_size,
                              hipStream_t stream) {
    const float* x    = (const float*)d_in[0];
    const float* w_q  = (const float*)d_in[1];
    const float* w_kv = (const float*)d_in[2];
    const float* w_o  = (const float*)d_in[3];
    const float* kw   = (const float*)d_in[4];
    float* out = (float*)d_out;

    char* ws = (char*)d_ws;
    short* xb    = (short*)(ws);                        // 4096x1024 bf16 : 8 MB
    short* wqkvt = (short*)(ws + ( 8u << 20));          // 2048x1024 bf16 : 4 MB
    short* wot   = (short*)(ws + (12u << 20));          // 1024x1024 bf16 : 2 MB
    short* qp    = (short*)(ws + (14u << 20));          // q' [4096][1024] : 8 MB
    short* kvb   = (short*)(ws + (22u << 20));          // kv [4096][1024] : 8 MB
    short* kvT   = (short*)(ws + (30u << 20));          // kvT [64bh*64v][1024 l] : 8 MB
    short* yb    = (short*)(ws + (38u << 20));          // y  [4096][1024] : 8 MB

    // weights transpose + x conversion, single launch
    prep_kernel<<<dim3(32, 32, 7), dim3(32, 8), 0, stream>>>(
        x, w_q, w_kv, w_o, xb, wqkvt, wot);

    // projections: M=4096, N=2048, K=1024 -> q' (kw folded), kv, kvT (LDS-transposed)
    // 128x128 tiles, 64x64/wave, dbuf, XCD-chunked swizzle: grid (16,32)
    gemm_proj_kernel<<<dim3(16, 32), 256, 0, stream>>>(
        xb, wqkvt, kw, qp, kvb, kvT);

    // attention (pair-balanced, chain-merged, bh-colocating XCD swizzle)
    attn_kernel<<<dim3(8, BATCH * NH), 256, 0, stream>>>(qp, kvb, kvT, yb);

    // output: M=4096, N=1024, K=1024 (128x128 tiles, dbuf, XCD-chunked swizzle)
    gemm_out_kernel<<<dim3(8, 32), 256, 0, stream>>>(yb, wot, out);
}